// Round 1
// baseline (271.503 us; speedup 1.0000x reference)
//
#include <hip/hip_runtime.h>

#define B_ 2
#define L_ 2048
#define H_ 1024
#define NH_ 16
#define HD_ 64
#define M_ 4096

using short8 = __attribute__((__ext_vector_type__(8))) short;
using f32x4 = __attribute__((__ext_vector_type__(4))) float;
typedef unsigned short u16;

__device__ __forceinline__ u16 f2bf(float f) {
  union { float f; unsigned u; } x{f};
  unsigned u = x.u;
  u = u + 0x7FFFu + ((u >> 16) & 1u);  // round-to-nearest-even
  return (u16)(u >> 16);
}

__device__ __forceinline__ void gld16(const void* g, void* l) {
  __builtin_amdgcn_global_load_lds(
      (const __attribute__((address_space(1))) void*)g,
      (__attribute__((address_space(3))) void*)l, 16, 0, 0);
}

#define MFMA16(a, b, c) __builtin_amdgcn_mfma_f32_16x16x32_bf16((a), (b), (c), 0, 0, 0)

// ---------------- cast f32 -> bf16 ----------------
__global__ void castk(const float* __restrict__ src, u16* __restrict__ dst, int n) {
  int i = (blockIdx.x * 256 + threadIdx.x) * 4;
  if (i < n) {
    float4 v = *(const float4*)(src + i);
    ushort4 o = make_ushort4(f2bf(v.x), f2bf(v.y), f2bf(v.z), f2bf(v.w));
    *(ushort4*)(dst + i) = o;
  }
}

// ---------------- fused QKV GEMM: [4096,1024] x [3072,1024]^T ----------------
// q,k written [b,h,l,d]; v written transposed [b,h,d,l]
__global__ __launch_bounds__(256) void gemm_qkv(
    const u16* __restrict__ A, const u16* __restrict__ W,
    const float* __restrict__ bq, const float* __restrict__ bk, const float* __restrict__ bv,
    u16* __restrict__ qg, u16* __restrict__ kg, u16* __restrict__ vTg) {
  __shared__ u16 As[128 * 64];
  __shared__ u16 Bs[128 * 64];
  const int tid = threadIdx.x;
  const int lane = tid & 63;
  const int wave = tid >> 6;
  const int wrow = (wave >> 1) * 64;
  const int wcol = (wave & 1) * 64;
  const int m0 = blockIdx.y * 128;
  const int n0 = blockIdx.x * 128;
  const int rr = tid >> 3;
  const int c8 = (tid & 7) * 8;
  f32x4 acc[4][4] = {};
  for (int kt = 0; kt < 1024; kt += 64) {
#pragma unroll
    for (int i = 0; i < 4; i++) {
      gld16(A + (size_t)(m0 + i * 32 + rr) * 1024 + kt + c8, (char*)As + i * 4096 + wave * 1024);
      gld16(W + (size_t)(n0 + i * 32 + rr) * 1024 + kt + c8, (char*)Bs + i * 4096 + wave * 1024);
    }
    __syncthreads();
#pragma unroll
    for (int kc = 0; kc < 2; kc++) {
      const int ko = kc * 32 + (lane >> 4) * 8;
      short8 af[4], bf[4];
#pragma unroll
      for (int mi = 0; mi < 4; mi++)
        af[mi] = *(const short8*)&As[(wrow + mi * 16 + (lane & 15)) * 64 + ko];
#pragma unroll
      for (int ni = 0; ni < 4; ni++)
        bf[ni] = *(const short8*)&Bs[(wcol + ni * 16 + (lane & 15)) * 64 + ko];
#pragma unroll
      for (int mi = 0; mi < 4; mi++)
#pragma unroll
        for (int ni = 0; ni < 4; ni++)
          acc[mi][ni] = MFMA16(af[mi], bf[ni], acc[mi][ni]);
    }
    __syncthreads();
  }
  const int which = n0 >> 10;  // 0=q 1=k 2=v, uniform per block
  const float* bias = which == 0 ? bq : (which == 1 ? bk : bv);
#pragma unroll
  for (int ni = 0; ni < 4; ni++) {
    const int n = n0 + wcol + ni * 16 + (lane & 15);
    const int nn = n & 1023;
    const int h = nn >> 6, d = nn & 63;
    const float bb = bias[nn];
#pragma unroll
    for (int mi = 0; mi < 4; mi++) {
      const int mb = m0 + wrow + mi * 16 + ((lane >> 4) << 2);
      const int b = mb >> 11;
      const int lq = mb & 2047;
      if (which == 2) {
        ushort4 pk = make_ushort4(f2bf(acc[mi][ni][0] + bb), f2bf(acc[mi][ni][1] + bb),
                                  f2bf(acc[mi][ni][2] + bb), f2bf(acc[mi][ni][3] + bb));
        *(ushort4*)&vTg[((size_t)(b * NH_ + h) * HD_ + d) * L_ + lq] = pk;
      } else {
        u16* dst = which == 0 ? qg : kg;
#pragma unroll
        for (int r = 0; r < 4; r++)
          dst[((size_t)(b * NH_ + h) * L_ + lq + r) * HD_ + d] = f2bf(acc[mi][ni][r] + bb);
      }
    }
  }
}

// ---------------- flash attention ----------------
// grid (L/128, B*NH), 256 threads; wave handles 32 q-rows x full d=64.
__global__ __launch_bounds__(256) void attn(
    const u16* __restrict__ qg, const u16* __restrict__ kg, const u16* __restrict__ vTg,
    const float* __restrict__ tau, const float* __restrict__ delta,
    u16* __restrict__ ctxg) {
  __shared__ u16 Ks[32 * 64];    // [key][d]
  __shared__ u16 VTs[64 * 32];   // [d][key]
  __shared__ u16 Plds[4][32 * 32];
  const int tid = threadIdx.x;
  const int lane = tid & 63;
  const int wave = tid >> 6;
  const int bh = blockIdx.y;
  const int b = bh >> 4;
  const int h = bh & 15;
  const int q0 = blockIdx.x * 128 + wave * 32;
  const float tau8 = tau[b] * 0.125f;
  const u16* qb = qg + (size_t)bh * L_ * HD_;
  const u16* kb = kg + (size_t)bh * L_ * HD_;
  const u16* vb = vTg + (size_t)bh * HD_ * L_;
  const float* db = delta + (size_t)b * L_;

  short8 qf[2][2];
#pragma unroll
  for (int mt = 0; mt < 2; mt++)
#pragma unroll
    for (int kc = 0; kc < 2; kc++)
      qf[mt][kc] = *(const short8*)&qb[(size_t)(q0 + mt * 16 + (lane & 15)) * 64 + kc * 32 + (lane >> 4) * 8];

  f32x4 acc[2][4] = {};
  float mrow[2][4], lrow[2][4];
#pragma unroll
  for (int mt = 0; mt < 2; mt++)
#pragma unroll
    for (int r = 0; r < 4; r++) { mrow[mt][r] = -__builtin_inff(); lrow[mt][r] = 0.f; }

  const int krow = tid >> 3, kc8 = (tid & 7) * 8;   // K staging map
  const int vd = tid >> 2, vk8 = (tid & 3) * 8;     // VT staging map

  for (int j0 = 0; j0 < L_; j0 += 32) {
    gld16(kb + (size_t)(j0 + krow) * 64 + kc8, (char*)Ks + wave * 1024);
    gld16(vb + (size_t)vd * L_ + j0 + vk8, (char*)VTs + wave * 1024);
    __syncthreads();

    // S = Q K^T  (rows=q, cols=key)
    f32x4 s[2][2] = {};
#pragma unroll
    for (int nt = 0; nt < 2; nt++) {
      short8 kf[2];
#pragma unroll
      for (int kc = 0; kc < 2; kc++)
        kf[kc] = *(const short8*)&Ks[(nt * 16 + (lane & 15)) * 64 + kc * 32 + (lane >> 4) * 8];
#pragma unroll
      for (int mt = 0; mt < 2; mt++)
#pragma unroll
        for (int kc = 0; kc < 2; kc++)
          s[mt][nt] = MFMA16(qf[mt][kc], kf[kc], s[mt][nt]);
    }
    float dl0 = db[j0 + (lane & 15)] * 0.125f;
    float dl1 = db[j0 + 16 + (lane & 15)] * 0.125f;

#pragma unroll
    for (int mt = 0; mt < 2; mt++) {
#pragma unroll
      for (int r = 0; r < 4; r++) {
        float s0 = s[mt][0][r] * tau8 + dl0;
        float s1 = s[mt][1][r] * tau8 + dl1;
        float mx = fmaxf(s0, s1);
        mx = fmaxf(mx, __shfl_xor(mx, 1));
        mx = fmaxf(mx, __shfl_xor(mx, 2));
        mx = fmaxf(mx, __shfl_xor(mx, 4));
        mx = fmaxf(mx, __shfl_xor(mx, 8));
        float mnew = fmaxf(mrow[mt][r], mx);
        float alpha = __expf(mrow[mt][r] - mnew);
        mrow[mt][r] = mnew;
        float p0 = __expf(s0 - mnew);
        float p1 = __expf(s1 - mnew);
        float rs = p0 + p1;
        rs += __shfl_xor(rs, 1);
        rs += __shfl_xor(rs, 2);
        rs += __shfl_xor(rs, 4);
        rs += __shfl_xor(rs, 8);
        lrow[mt][r] = lrow[mt][r] * alpha + rs;
#pragma unroll
        for (int nt2 = 0; nt2 < 4; nt2++) acc[mt][nt2][r] *= alpha;
        const int prow = mt * 16 + (lane >> 4) * 4 + r;
        Plds[wave][prow * 32 + (lane & 15)] = f2bf(p0);
        Plds[wave][prow * 32 + 16 + (lane & 15)] = f2bf(p1);
      }
    }
    asm volatile("s_waitcnt lgkmcnt(0)" ::: "memory");

    // ctx += P V   (A rows=q from Plds, B cols=d from VTs)
    short8 pf[2], vf[4];
#pragma unroll
    for (int mt = 0; mt < 2; mt++)
      pf[mt] = *(const short8*)&Plds[wave][(mt * 16 + (lane & 15)) * 32 + (lane >> 4) * 8];
#pragma unroll
    for (int nt = 0; nt < 4; nt++)
      vf[nt] = *(const short8*)&VTs[(nt * 16 + (lane & 15)) * 32 + (lane >> 4) * 8];
#pragma unroll
    for (int mt = 0; mt < 2; mt++)
#pragma unroll
      for (int nt = 0; nt < 4; nt++)
        acc[mt][nt] = MFMA16(pf[mt], vf[nt], acc[mt][nt]);
    __syncthreads();
  }

#pragma unroll
  for (int mt = 0; mt < 2; mt++) {
#pragma unroll
    for (int r = 0; r < 4; r++) {
      const float inv = 1.0f / lrow[mt][r];
      const int lq = q0 + mt * 16 + (lane >> 4) * 4 + r;
#pragma unroll
      for (int nt = 0; nt < 4; nt++) {
        const int d = nt * 16 + (lane & 15);
        ctxg[(size_t)(b * L_ + lq) * H_ + h * 64 + d] = f2bf(acc[mt][nt][r] * inv);
      }
    }
  }
}

// ---------------- output GEMM: ctx[4096,1024] x Wo[1024,1024]^T + bo -> f32 ----------------
__global__ __launch_bounds__(256) void gemm_out(
    const u16* __restrict__ A, const u16* __restrict__ W,
    const float* __restrict__ bo, float* __restrict__ out) {
  __shared__ u16 As[128 * 64];
  __shared__ u16 Bs[128 * 64];
  const int tid = threadIdx.x;
  const int lane = tid & 63;
  const int wave = tid >> 6;
  const int wrow = (wave >> 1) * 64;
  const int wcol = (wave & 1) * 64;
  const int m0 = blockIdx.y * 128;
  const int n0 = blockIdx.x * 128;
  const int rr = tid >> 3;
  const int c8 = (tid & 7) * 8;
  f32x4 acc[4][4] = {};
  for (int kt = 0; kt < 1024; kt += 64) {
#pragma unroll
    for (int i = 0; i < 4; i++) {
      gld16(A + (size_t)(m0 + i * 32 + rr) * 1024 + kt + c8, (char*)As + i * 4096 + wave * 1024);
      gld16(W + (size_t)(n0 + i * 32 + rr) * 1024 + kt + c8, (char*)Bs + i * 4096 + wave * 1024);
    }
    __syncthreads();
#pragma unroll
    for (int kc = 0; kc < 2; kc++) {
      const int ko = kc * 32 + (lane >> 4) * 8;
      short8 af[4], bf[4];
#pragma unroll
      for (int mi = 0; mi < 4; mi++)
        af[mi] = *(const short8*)&As[(wrow + mi * 16 + (lane & 15)) * 64 + ko];
#pragma unroll
      for (int ni = 0; ni < 4; ni++)
        bf[ni] = *(const short8*)&Bs[(wcol + ni * 16 + (lane & 15)) * 64 + ko];
#pragma unroll
      for (int mi = 0; mi < 4; mi++)
#pragma unroll
        for (int ni = 0; ni < 4; ni++)
          acc[mi][ni] = MFMA16(af[mi], bf[ni], acc[mi][ni]);
    }
    __syncthreads();
  }
#pragma unroll
  for (int ni = 0; ni < 4; ni++) {
    const int n = n0 + wcol + ni * 16 + (lane & 15);
    const float bb = bo[n];
#pragma unroll
    for (int mi = 0; mi < 4; mi++) {
      const int mb = m0 + wrow + mi * 16 + ((lane >> 4) << 2);
#pragma unroll
      for (int r = 0; r < 4; r++)
        out[(size_t)(mb + r) * 1024 + n] = acc[mi][ni][r] + bb;
    }
  }
}

extern "C" void kernel_launch(void* const* d_in, const int* in_sizes, int n_in,
                              void* d_out, int out_size, void* d_ws, size_t ws_size,
                              hipStream_t stream) {
  const float* hs = (const float*)d_in[0];
  const float* tau = (const float*)d_in[1];
  const float* delta = (const float*)d_in[2];
  const float* Wq = (const float*)d_in[3];
  const float* bq = (const float*)d_in[4];
  const float* Wk = (const float*)d_in[5];
  const float* bk = (const float*)d_in[6];
  const float* Wv = (const float*)d_in[7];
  const float* bv = (const float*)d_in[8];
  const float* Wo = (const float*)d_in[9];
  const float* bo = (const float*)d_in[10];
  float* out = (float*)d_out;

  u16* ws = (u16*)d_ws;
  u16* hsb  = ws;                   // 4194304
  u16* wqkv = ws + 4194304;         // 3145728 (Wq|Wk|Wv)
  u16* wob  = ws + 7340032;         // 1048576
  u16* qg   = ws + 8388608;         // 4194304
  u16* kg   = ws + 12582912;        // 4194304
  u16* vTg  = ws + 16777216;        // 4194304
  u16* ctxg = ws + 20971520;        // 4194304

  castk<<<4096, 256, 0, stream>>>(hs, hsb, 4194304);
  castk<<<1024, 256, 0, stream>>>(Wq, wqkv, 1048576);
  castk<<<1024, 256, 0, stream>>>(Wk, wqkv + 1048576, 1048576);
  castk<<<1024, 256, 0, stream>>>(Wv, wqkv + 2097152, 1048576);
  castk<<<1024, 256, 0, stream>>>(Wo, wob, 1048576);

  gemm_qkv<<<dim3(24, 32), 256, 0, stream>>>(hsb, wqkv, bq, bk, bv, qg, kg, vTg);
  attn<<<dim3(16, 32), 256, 0, stream>>>(qg, kg, vTg, tau, delta, ctxg);
  gemm_out<<<dim3(8, 32), 256, 0, stream>>>(ctxg, wob, bo, out);
}

// Round 2
// 170.464 us; speedup vs baseline: 1.5927x; 1.5927x over previous
//
#include <hip/hip_runtime.h>

#define B_ 2
#define L_ 2048
#define H_ 1024
#define NH_ 16
#define HD_ 64

using short8 = __attribute__((__ext_vector_type__(8))) short;
using f32x4 = __attribute__((__ext_vector_type__(4))) float;
using f32x16 = __attribute__((__ext_vector_type__(16))) float;
typedef unsigned short u16;
typedef unsigned int u32;

__device__ __forceinline__ u16 f2bf(float f) {
  union { float f; unsigned u; } x{f};
  unsigned u = x.u;
  u = u + 0x7FFFu + ((u >> 16) & 1u);  // round-to-nearest-even
  return (u16)(u >> 16);
}

__device__ __forceinline__ void gld16(const void* g, void* l) {
  __builtin_amdgcn_global_load_lds(
      (const __attribute__((address_space(1))) void*)g,
      (__attribute__((address_space(3))) void*)l, 16, 0, 0);
}

#define MFMA16(a, b, c) __builtin_amdgcn_mfma_f32_16x16x32_bf16((a), (b), (c), 0, 0, 0)
#define MFMA32(a, b, c) __builtin_amdgcn_mfma_f32_32x32x16_bf16((a), (b), (c), 0, 0, 0)

// ---------------- cast f32 -> bf16 ----------------
__global__ void castk(const float* __restrict__ src, u16* __restrict__ dst, int n) {
  int i = (blockIdx.x * 256 + threadIdx.x) * 4;
  if (i < n) {
    float4 v = *(const float4*)(src + i);
    ushort4 o = make_ushort4(f2bf(v.x), f2bf(v.y), f2bf(v.z), f2bf(v.w));
    *(ushort4*)(dst + i) = o;
  }
}

// delta -> delta * 0.125 * log2(e)
__global__ void prep_delta(const float* __restrict__ d, float* __restrict__ o, int n) {
  int i = blockIdx.x * 256 + threadIdx.x;
  if (i < n) o[i] = d[i] * 0.18033688011112042f;
}

// ---------------- fused QKV GEMM: [4096,1024] x [3072,1024]^T ----------------
// q (pre-scaled by tau*0.125*log2e), k written [b,h,l,d]; v written transposed [b,h,d,l]
__global__ __launch_bounds__(256) void gemm_qkv(
    const u16* __restrict__ A, const u16* __restrict__ W,
    const float* __restrict__ bq, const float* __restrict__ bk, const float* __restrict__ bv,
    const float* __restrict__ tau,
    u16* __restrict__ qg, u16* __restrict__ kg, u16* __restrict__ vTg) {
  __shared__ u16 As[128 * 64];
  __shared__ u16 Bs[128 * 64];
  const int tid = threadIdx.x;
  const int lane = tid & 63;
  const int wave = tid >> 6;
  const int wrow = (wave >> 1) * 64;
  const int wcol = (wave & 1) * 64;
  const int m0 = blockIdx.y * 128;
  const int n0 = blockIdx.x * 128;
  const int rr = tid >> 3;
  const int c8 = (tid & 7) * 8;
  f32x4 acc[4][4] = {};
  for (int kt = 0; kt < 1024; kt += 64) {
#pragma unroll
    for (int i = 0; i < 4; i++) {
      gld16(A + (size_t)(m0 + i * 32 + rr) * 1024 + kt + c8, (char*)As + i * 4096 + wave * 1024);
      gld16(W + (size_t)(n0 + i * 32 + rr) * 1024 + kt + c8, (char*)Bs + i * 4096 + wave * 1024);
    }
    __syncthreads();
#pragma unroll
    for (int kc = 0; kc < 2; kc++) {
      const int ko = kc * 32 + (lane >> 4) * 8;
      short8 af[4], bf[4];
#pragma unroll
      for (int mi = 0; mi < 4; mi++)
        af[mi] = *(const short8*)&As[(wrow + mi * 16 + (lane & 15)) * 64 + ko];
#pragma unroll
      for (int ni = 0; ni < 4; ni++)
        bf[ni] = *(const short8*)&Bs[(wcol + ni * 16 + (lane & 15)) * 64 + ko];
#pragma unroll
      for (int mi = 0; mi < 4; mi++)
#pragma unroll
        for (int ni = 0; ni < 4; ni++)
          acc[mi][ni] = MFMA16(af[mi], bf[ni], acc[mi][ni]);
    }
    __syncthreads();
  }
  const int which = n0 >> 10;  // 0=q 1=k 2=v, uniform per block
  const int b_blk = m0 >> 11;
  const float scl = (which == 0) ? tau[b_blk] * 0.18033688011112042f : 1.0f;
  const float* bias = which == 0 ? bq : (which == 1 ? bk : bv);
#pragma unroll
  for (int ni = 0; ni < 4; ni++) {
    const int n = n0 + wcol + ni * 16 + (lane & 15);
    const int nn = n & 1023;
    const int h = nn >> 6, d = nn & 63;
    const float bb = bias[nn];
#pragma unroll
    for (int mi = 0; mi < 4; mi++) {
      const int mb = m0 + wrow + mi * 16 + ((lane >> 4) << 2);
      const int b = mb >> 11;
      const int lq = mb & 2047;
      if (which == 2) {
        ushort4 pk = make_ushort4(f2bf(acc[mi][ni][0] + bb), f2bf(acc[mi][ni][1] + bb),
                                  f2bf(acc[mi][ni][2] + bb), f2bf(acc[mi][ni][3] + bb));
        *(ushort4*)&vTg[((size_t)(b * NH_ + h) * HD_ + d) * L_ + lq] = pk;
      } else {
        u16* dst = which == 0 ? qg : kg;
#pragma unroll
        for (int r = 0; r < 4; r++)
          dst[((size_t)(b * NH_ + h) * L_ + lq + r) * HD_ + d] = f2bf((acc[mi][ni][r] + bb) * scl);
      }
    }
  }
}

// ---------------- flash attention, swapped-QK^T 32x32x16 structure ----------------
// grid (L/128, B*NH), 256 threads; each wave owns 32 q-rows, KVBLK=64 double-buffered.
__global__ __launch_bounds__(256) void attn(
    const u16* __restrict__ qg, const u16* __restrict__ kg, const u16* __restrict__ vTg,
    const float* __restrict__ dsc, u16* __restrict__ ctxg) {
  // per buffer: 8 K blocks (2 ktile x 4 ks) + 8 V blocks (2 kt x 2 dt x 2 ks2), 1KB each
  __shared__ u16 lds[2][8192];
  const int tid = threadIdx.x;
  const int lane = tid & 63;
  const int wv = tid >> 6;
  const int lane31 = lane & 31;
  const int hi = lane >> 5;
  const int bh = blockIdx.y;
  const int b = bh >> 4;
  const int h = bh & 15;
  const int q0 = blockIdx.x * 128 + wv * 32;
  const u16* qb = qg + (size_t)bh * L_ * HD_;
  const u16* kb = kg + (size_t)bh * L_ * HD_;
  const u16* vb = vTg + (size_t)bh * HD_ * L_;
  const float* db = dsc + (size_t)b * L_;

  // Q fragments (B-operand): lane holds Q[q0+lane31][ks*16 + hi*8 .. +7]
  short8 qf[4];
#pragma unroll
  for (int ks = 0; ks < 4; ks++)
    qf[ks] = *(const short8*)&qb[(size_t)(q0 + lane31) * 64 + ks * 16 + hi * 8];

  f32x16 acc[2] = {};  // ctx^T: [dtile] rows d=crow(r,hi), col q=lane31
  float mrun = -__builtin_inff(), lrun = 0.f;

  const int i0 = 2 * wv, i1 = 2 * wv + 1;  // this wave's staging blocks

#define STAGE(bufi, j0)                                                                   \
  {                                                                                       \
    u16* bp = lds[bufi];                                                                  \
    {                                                                                     \
      const int kt = i0 >> 2, ks = i0 & 3;                                                \
      gld16(kb + (size_t)((j0) + kt * 32 + lane31) * 64 + ks * 16 + hi * 8,               \
            bp + i0 * 512 + lane * 8);                                                    \
    }                                                                                     \
    {                                                                                     \
      const int kt = i1 >> 2, ks = i1 & 3;                                                \
      gld16(kb + (size_t)((j0) + kt * 32 + lane31) * 64 + ks * 16 + hi * 8,               \
            bp + i1 * 512 + lane * 8);                                                    \
    }                                                                                     \
    {                                                                                     \
      const int kt = i0 >> 2, dt = (i0 >> 1) & 1, ks2 = i0 & 1;                           \
      gld16(vb + (size_t)(dt * 32 + lane31) * L_ + (j0) + kt * 32 + ks2 * 16 + hi * 8,    \
            bp + (8 + i0) * 512 + lane * 8);                                              \
    }                                                                                     \
    {                                                                                     \
      const int kt = i1 >> 2, dt = (i1 >> 1) & 1, ks2 = i1 & 1;                           \
      gld16(vb + (size_t)(dt * 32 + lane31) * L_ + (j0) + kt * 32 + ks2 * 16 + hi * 8,    \
            bp + (8 + i1) * 512 + lane * 8);                                              \
    }                                                                                     \
  }

  STAGE(0, 0);
  __syncthreads();
  int cur = 0;
  for (int jt = 0; jt < L_ / 64; jt++) {
    const int j0 = jt * 64;
    if (jt + 1 < L_ / 64) STAGE(cur ^ 1, j0 + 64);
    const u16* bp = lds[cur];
#pragma unroll
    for (int kt = 0; kt < 2; kt++) {
      // S^T = K . Q^T : lane holds col q=lane31, rows key=crow(r,hi)
      f32x16 s = {};
#pragma unroll
      for (int ks = 0; ks < 4; ks++) {
        short8 kf = *(const short8*)&bp[(kt * 4 + ks) * 512 + lane * 8];
        s = MFMA32(kf, qf[ks], s);
      }
      // add pre-scaled delta (log2 units)
      float sv[16];
#pragma unroll
      for (int g = 0; g < 4; g++) {
        float4 dl = *(const float4*)&db[j0 + kt * 32 + g * 8 + hi * 4];
        sv[g * 4 + 0] = s[g * 4 + 0] + dl.x;
        sv[g * 4 + 1] = s[g * 4 + 1] + dl.y;
        sv[g * 4 + 2] = s[g * 4 + 2] + dl.z;
        sv[g * 4 + 3] = s[g * 4 + 3] + dl.w;
      }
      // row max (16 local + 1 cross-half shuffle)
      float t0 = fmaxf(fmaxf(sv[0], sv[1]), fmaxf(sv[2], sv[3]));
      float t1 = fmaxf(fmaxf(sv[4], sv[5]), fmaxf(sv[6], sv[7]));
      float t2 = fmaxf(fmaxf(sv[8], sv[9]), fmaxf(sv[10], sv[11]));
      float t3 = fmaxf(fmaxf(sv[12], sv[13]), fmaxf(sv[14], sv[15]));
      float pmax = fmaxf(fmaxf(t0, t1), fmaxf(t2, t3));
      pmax = fmaxf(pmax, __shfl_xor(pmax, 32));
      // defer-max (THR = 8 * log2e ~ 11.54)
      if (!__all(pmax - mrun <= 11.5f)) {
        float mnew = fmaxf(mrun, pmax);
        float al = __builtin_amdgcn_exp2f(mrun - mnew);
        mrun = mnew;
        lrun *= al;
#pragma unroll
        for (int dt = 0; dt < 2; dt++)
#pragma unroll
          for (int r = 0; r < 16; r++) acc[dt][r] *= al;
      }
      float p[16];
#pragma unroll
      for (int r = 0; r < 16; r++) p[r] = __builtin_amdgcn_exp2f(sv[r] - mrun);
      float r0 = (p[0] + p[1]) + (p[2] + p[3]);
      float r1 = (p[4] + p[5]) + (p[6] + p[7]);
      float r2 = (p[8] + p[9]) + (p[10] + p[11]);
      float r3 = (p[12] + p[13]) + (p[14] + p[15]);
      float rs = (r0 + r1) + (r2 + r3);
      rs += __shfl_xor(rs, 32);
      lrun += rs;
      // T12: pack to bf16 pairs, permlane32_swap to build PV B-fragments in-register
      u32 pk[8];
#pragma unroll
      for (int i = 0; i < 8; i++)
        asm("v_cvt_pk_bf16_f32 %0, %1, %2" : "=v"(pk[i]) : "v"(p[2 * i]), "v"(p[2 * i + 1]));
      asm volatile("v_permlane32_swap_b32 %0, %1" : "+v"(pk[0]), "+v"(pk[2]));
      asm volatile("v_permlane32_swap_b32 %0, %1" : "+v"(pk[1]), "+v"(pk[3]));
      asm volatile("v_permlane32_swap_b32 %0, %1" : "+v"(pk[4]), "+v"(pk[6]));
      asm volatile("v_permlane32_swap_b32 %0, %1" : "+v"(pk[5]), "+v"(pk[7]));
      union U8 { u32 u[4]; short8 s; } f0, f1;
      f0.u[0] = pk[0]; f0.u[1] = pk[1]; f0.u[2] = pk[2]; f0.u[3] = pk[3];
      f1.u[0] = pk[4]; f1.u[1] = pk[5]; f1.u[2] = pk[6]; f1.u[3] = pk[7];
      // ctx^T += V^T . P
#pragma unroll
      for (int ks2 = 0; ks2 < 2; ks2++) {
        short8 pf = ks2 ? f1.s : f0.s;
#pragma unroll
        for (int dt = 0; dt < 2; dt++) {
          short8 vf = *(const short8*)&bp[(8 + kt * 4 + dt * 2 + ks2) * 512 + lane * 8];
          acc[dt] = MFMA32(vf, pf, acc[dt]);
        }
      }
    }
    __syncthreads();
    cur ^= 1;
  }

  // epilogue: transpose ctx^T -> ctx via swizzled per-wave LDS tile, coalesced store
  __syncthreads();
  u16* tw = lds[0] + wv * 2048;  // 4KB per wave: [32 q][64 d] bf16, XOR-swizzled
  const float inv = 1.0f / lrun;
#pragma unroll
  for (int dt = 0; dt < 2; dt++)
#pragma unroll
    for (int g = 0; g < 4; g++) {
      ushort4 w4 = make_ushort4(f2bf(acc[dt][g * 4 + 0] * inv), f2bf(acc[dt][g * 4 + 1] * inv),
                                f2bf(acc[dt][g * 4 + 2] * inv), f2bf(acc[dt][g * 4 + 3] * inv));
      const int d0 = dt * 32 + g * 8 + hi * 4;
      const int byte = (lane31 * 128 + d0 * 2) ^ ((lane31 & 15) << 3);
      *(ushort4*)((char*)tw + byte) = w4;
    }
  __syncthreads();
  const size_t obase = ((size_t)b * L_ + blockIdx.x * 128 + wv * 32) * 1024 + h * 64;
#pragma unroll
  for (int i = 0; i < 16; i++) {
    const int qr = 2 * i + hi;
    const int byte = (qr * 128 + lane31 * 4) ^ ((qr & 15) << 3);
    const u32 val = *(const u32*)((const char*)tw + byte);
    *(u32*)&ctxg[obase + (size_t)qr * 1024 + lane31 * 2] = val;
  }
}

// ---------------- output GEMM: ctx[4096,1024] x Wo[1024,1024]^T + bo -> f32 ----------------
__global__ __launch_bounds__(256) void gemm_out(
    const u16* __restrict__ A, const u16* __restrict__ W,
    const float* __restrict__ bo, float* __restrict__ out) {
  __shared__ u16 As[128 * 64];
  __shared__ u16 Bs[128 * 64];
  const int tid = threadIdx.x;
  const int lane = tid & 63;
  const int wave = tid >> 6;
  const int wrow = (wave >> 1) * 64;
  const int wcol = (wave & 1) * 64;
  const int m0 = blockIdx.y * 128;
  const int n0 = blockIdx.x * 128;
  const int rr = tid >> 3;
  const int c8 = (tid & 7) * 8;
  f32x4 acc[4][4] = {};
  for (int kt = 0; kt < 1024; kt += 64) {
#pragma unroll
    for (int i = 0; i < 4; i++) {
      gld16(A + (size_t)(m0 + i * 32 + rr) * 1024 + kt + c8, (char*)As + i * 4096 + wave * 1024);
      gld16(W + (size_t)(n0 + i * 32 + rr) * 1024 + kt + c8, (char*)Bs + i * 4096 + wave * 1024);
    }
    __syncthreads();
#pragma unroll
    for (int kc = 0; kc < 2; kc++) {
      const int ko = kc * 32 + (lane >> 4) * 8;
      short8 af[4], bf[4];
#pragma unroll
      for (int mi = 0; mi < 4; mi++)
        af[mi] = *(const short8*)&As[(wrow + mi * 16 + (lane & 15)) * 64 + ko];
#pragma unroll
      for (int ni = 0; ni < 4; ni++)
        bf[ni] = *(const short8*)&Bs[(wcol + ni * 16 + (lane & 15)) * 64 + ko];
#pragma unroll
      for (int mi = 0; mi < 4; mi++)
#pragma unroll
        for (int ni = 0; ni < 4; ni++)
          acc[mi][ni] = MFMA16(af[mi], bf[ni], acc[mi][ni]);
    }
    __syncthreads();
  }
#pragma unroll
  for (int ni = 0; ni < 4; ni++) {
    const int n = n0 + wcol + ni * 16 + (lane & 15);
    const float bb = bo[n];
#pragma unroll
    for (int mi = 0; mi < 4; mi++) {
      const int mb = m0 + wrow + mi * 16 + ((lane >> 4) << 2);
#pragma unroll
      for (int r = 0; r < 4; r++)
        out[(size_t)(mb + r) * 1024 + n] = acc[mi][ni][r] + bb;
    }
  }
}

extern "C" void kernel_launch(void* const* d_in, const int* in_sizes, int n_in,
                              void* d_out, int out_size, void* d_ws, size_t ws_size,
                              hipStream_t stream) {
  const float* hs = (const float*)d_in[0];
  const float* tau = (const float*)d_in[1];
  const float* delta = (const float*)d_in[2];
  const float* Wq = (const float*)d_in[3];
  const float* bq = (const float*)d_in[4];
  const float* Wk = (const float*)d_in[5];
  const float* bk = (const float*)d_in[6];
  const float* Wv = (const float*)d_in[7];
  const float* bv = (const float*)d_in[8];
  const float* Wo = (const float*)d_in[9];
  const float* bo = (const float*)d_in[10];
  float* out = (float*)d_out;

  u16* ws = (u16*)d_ws;
  u16* hsb  = ws;                   // 4194304
  u16* wqkv = ws + 4194304;         // 3145728 (Wq|Wk|Wv)
  u16* wob  = ws + 7340032;         // 1048576
  u16* qg   = ws + 8388608;         // 4194304
  u16* kg   = ws + 12582912;        // 4194304
  u16* vTg  = ws + 16777216;        // 4194304
  u16* ctxg = ws + 20971520;        // 4194304
  float* dsc = (float*)(ws + 25165824);  // 4096 floats

  castk<<<4096, 256, 0, stream>>>(hs, hsb, 4194304);
  castk<<<1024, 256, 0, stream>>>(Wq, wqkv, 1048576);
  castk<<<1024, 256, 0, stream>>>(Wk, wqkv + 1048576, 1048576);
  castk<<<1024, 256, 0, stream>>>(Wv, wqkv + 2097152, 1048576);
  castk<<<1024, 256, 0, stream>>>(Wo, wob, 1048576);
  prep_delta<<<16, 256, 0, stream>>>(delta, dsc, 4096);

  gemm_qkv<<<dim3(24, 32), 256, 0, stream>>>(hsb, wqkv, bq, bk, bv, tau, qg, kg, vTg);
  attn<<<dim3(16, 32), 256, 0, stream>>>(qg, kg, vTg, dsc, ctxg);
  gemm_out<<<dim3(8, 32), 256, 0, stream>>>(ctxg, wob, bo, out);
}